// Round 10
// baseline (281.693 us; speedup 1.0000x reference)
//
#include <hip/hip_runtime.h>
#include <hip/hip_fp16.h>
#include <math.h>

// ---------------------------------------------------------------------------
// GCN 3-layer: out = sigmoid( L3(relu(L2(relu(L1(x))))) @ Wl + bl )
// hs = half((x @ W) * dinv[row]);  z = relu(dinv[d]*(hs[d]+sum hs[s])+b)
// fp32 accumulate, fp16 storage.
// CLOSED levers on agg1 (floor 64.3us, 435MB delivered / 188MB L2-fill at
// the random-256B fabric rate): +waves (R1 flat), +ILP (R3 worse),
// -compulsory bytes (R4 worse), nt/L2-bypass (R8 worse). Harness re-poison
// fill = 40.5us fixed in-window (R6). CSR = 2-pass fixed-CAP bucket build
// (R9, -11.5us). R9 best = 274.75us.
// R10: agg2/agg3 may be divergence/latency-bound (traffic ~2-4x below the
// fabric rate; 4-8 lanes/node; wave runs at max-degree of its nodes).
// Give them 2 lanes per (node,fg) -- each gathers half the edge list,
// combine via one shfl_xor butterfly. Lane-parallel (occupancy-neutral,
// avoids R3's VGPR failure). agg1 kept byte-identical as sentinel.
// Pre-committed: ~255-265 => was latency-bound; flat => ROOFLINE next.
// ---------------------------------------------------------------------------

#define BSHIFT 8
#define BNODES (1 << BSHIFT)
#define SRCBITS 17
#define MAXB 512
#define CAP 8192

typedef _Float16 half8 __attribute__((ext_vector_type(8)));
typedef float floatx4 __attribute__((ext_vector_type(4)));

union H8 { float4 f4; __half2 h2[4]; };

// ---- k_bucket: blocks [0,nb) partition 4096 edges each into fixed-CAP
// bucket regions; blocks [nb, nb+npack) pack W1/W2/W3 (launch fold). ----
__global__ __launch_bounds__(256) void k_bucket(const int* __restrict__ src,
                                                const int* __restrict__ dst, int E,
                                                int* __restrict__ cursor,
                                                unsigned int* __restrict__ edgebuf,
                                                int B, int nb,
                                                const float* __restrict__ W1,
                                                const float* __restrict__ W2,
                                                const float* __restrict__ W3,
                                                _Float16* __restrict__ P1,
                                                _Float16* __restrict__ P2,
                                                _Float16* __restrict__ P3) {
    int tid = threadIdx.x;
    if (blockIdx.x >= nb) {
        int e = (blockIdx.x - nb) * 256 + tid;
        const float* W; _Float16* P; int OUT, idx;
        if (e < 16384)      { W = W1; P = P1; OUT = 128; idx = e; }
        else if (e < 24576) { W = W2; P = P2; OUT = 64;  idx = e - 16384; }
        else if (e < 26624) { W = W3; P = P3; OUT = 32;  idx = e - 24576; }
        else return;
        int j = idx & 7;
        int lane = (idx >> 3) & 63;
        int rest = idx >> 9;
        int NT2 = OUT >> 4;
        int t = rest % NT2;
        int ss = rest / NT2;
        int k = ss * 32 + (lane >> 4) * 8 + j;
        int nn = t * 16 + (lane & 15);
        P[idx] = (_Float16)W[k * OUT + nn];
        return;
    }
    __shared__ int h[MAXB];
    __shared__ int pos_[MAXB];
    int base = blockIdx.x * 4096;
    int end = min(base + 4096, E);
    h[tid] = 0; h[tid + 256] = 0;
    __syncthreads();
    for (int i = base + tid; i < end; i += 256)
        atomicAdd(&h[dst[i] >> BSHIFT], 1);
    __syncthreads();
    if (tid < B) pos_[tid] = (h[tid] > 0) ? atomicAdd(&cursor[tid], h[tid]) : 0;
    int t2 = tid + 256;
    if (t2 < B) pos_[t2] = (h[t2] > 0) ? atomicAdd(&cursor[t2], h[t2]) : 0;
    __syncthreads();
    for (int i = base + tid; i < end; i += 256) {
        int d = dst[i];
        int b = d >> BSHIFT;
        unsigned int pk = ((unsigned int)(d & (BNODES - 1)) << SRCBITS) | (unsigned int)src[i];
        int pos = atomicAdd(&pos_[b], 1);
        if (pos < CAP) edgebuf[(size_t)b * CAP + pos] = pk;   // overflow guard
    }
}

// ---- k_build: per bucket, per-node counts + local scan -> strided CSR ----
__global__ __launch_bounds__(256) void k_build(const unsigned int* __restrict__ edgebuf,
                                               const int* __restrict__ cursor,
                                               int* __restrict__ row_ptr,
                                               int* __restrict__ rcnt,
                                               float* __restrict__ dinv,
                                               int* __restrict__ col, int n) {
    __shared__ int cnt[BNODES];
    __shared__ int s[BNODES];
    int b = blockIdx.x;
    int tid = threadIdx.x;
    int node0 = b << BSHIFT;
    int count = min(cursor[b], CAP);
    size_t ebase = (size_t)b * CAP;
    cnt[tid] = 0;
    __syncthreads();
    for (int i = tid; i < count; i += 256)
        atomicAdd(&cnt[edgebuf[ebase + i] >> SRCBITS], 1);
    __syncthreads();
    int c = cnt[tid];
    s[tid] = c;
    __syncthreads();
    for (int off = 1; off < 256; off <<= 1) {
        int t = (tid >= off) ? s[tid - off] : 0;
        __syncthreads();
        s[tid] += t;
        __syncthreads();
    }
    int p = b * CAP + s[tid] - c;     // absolute position in strided col[]
    int node = node0 + tid;
    if (node < n) {
        row_ptr[node] = p;
        rcnt[node] = c;
        dinv[node] = rsqrtf((float)(c + 1));
    }
    cnt[tid] = p;
    __syncthreads();
    for (int i = tid; i < count; i += 256) {
        unsigned int pk = edgebuf[ebase + i];
        int pos = atomicAdd(&cnt[pk >> SRCBITS], 1);
        col[pos] = (int)(pk & ((1u << SRCBITS) - 1));
    }
}

// ---------------- MFMA matmul (layer 1): hs = half((x@W)*dinv[row]) -------
template <int IN, int OUT>
__global__ __launch_bounds__(256) void k_matmul_mfma(const float* __restrict__ x,
                                                     const _Float16* __restrict__ Wpk,
                                                     const float* __restrict__ dinv,
                                                     __half* __restrict__ out, int n) {
    constexpr int S = IN / 32;
    constexpr int NT = OUT / 16;
    constexpr int TPW = NT / 2;
    constexpr int LDH = IN + 8;
    __shared__ _Float16 xs[32 * LDH];

    int tid = threadIdx.x;
    int rowbase = blockIdx.x * 32;

    constexpr int TOT = 32 * IN / 8;
    const float4* x4 = (const float4*)x;
    for (int i = tid; i < TOT; i += 256) {
        int r = i / (IN / 8), kg = i % (IN / 8);
        int row = rowbase + r;
        float4 a = make_float4(0.f, 0.f, 0.f, 0.f), b = a;
        if (row < n) {
            a = x4[(size_t)row * (IN / 4) + kg * 2 + 0];
            b = x4[(size_t)row * (IN / 4) + kg * 2 + 1];
        }
        _Float16* p = &xs[r * LDH + kg * 8];
        p[0] = (_Float16)a.x; p[1] = (_Float16)a.y;
        p[2] = (_Float16)a.z; p[3] = (_Float16)a.w;
        p[4] = (_Float16)b.x; p[5] = (_Float16)b.y;
        p[6] = (_Float16)b.z; p[7] = (_Float16)b.w;
    }
    __syncthreads();

    int lane = tid & 63;
    int wave = tid >> 6;
    int m = lane & 15, quad = lane >> 4;
    int rg = wave >> 1;
    int th = wave & 1;

    floatx4 acc[TPW];
#pragma unroll
    for (int t = 0; t < TPW; ++t) acc[t] = (floatx4){0.f, 0.f, 0.f, 0.f};

    const half8* Wf = (const half8*)Wpk;
#pragma unroll
    for (int s = 0; s < S; ++s) {
        half8 a = *(const half8*)&xs[(rg * 16 + m) * LDH + s * 32 + quad * 8];
#pragma unroll
        for (int t = 0; t < TPW; ++t) {
            half8 b = Wf[(s * NT + th * TPW + t) * 64 + lane];
            acc[t] = __builtin_amdgcn_mfma_f32_16x16x32_f16(a, b, acc[t], 0, 0, 0);
        }
    }

    int rbase = rowbase + rg * 16 + quad * 4;
#pragma unroll
    for (int r = 0; r < 4; ++r) {
        int row = rbase + r;
        if (row < n) {
            float dsc = dinv[row];
#pragma unroll
            for (int t = 0; t < TPW; ++t)
                out[(size_t)row * OUT + (th * TPW + t) * 16 + m] = __float2half(acc[t][r] * dsc);
        }
    }
}

// ------- fused: z = relu(dinv*(agg hs)+b) in LDS, then hs' = (z@W)*dinv ----
// 32 dst rows/block. HALVES=2: two lanes per (node,fg), each gathers half
// the edge list; combine via shfl_xor(1). HALVES=1 path is byte-identical
// to R9 (agg1 sentinel).
template <int F, int OUT, int TPB, int HALVES>
__global__ __launch_bounds__(TPB) void k_agg_mm(const __half* __restrict__ hs,
                                                const float* __restrict__ dinv,
                                                const float* __restrict__ bias,
                                                const int* __restrict__ row_ptr,
                                                const int* __restrict__ rcnt,
                                                const int* __restrict__ col,
                                                const _Float16* __restrict__ Wpk,
                                                __half* __restrict__ out, int n) {
    constexpr int S = F / 32;
    constexpr int NT = OUT / 16;
    constexpr int TPW = NT / 2;
    constexpr int LDH = F + 8;
    constexpr int LPN = F / 8;
    constexpr int TASKS = 32 * LPN * HALVES;
    __shared__ _Float16 zs[32 * LDH];

    int tid = threadIdx.x;
    int rowbase = blockIdx.x * 32;
    const float4* h4 = (const float4*)hs;

    // ---- aggregate 32 dst rows into LDS (fp32 acc, fp16 store) ----
    for (int task = tid; task < TASKS; task += TPB) {
        int h = task & (HALVES - 1);
        int fg = (task / HALVES) % LPN;
        int nl = task / (HALVES * LPN);
        int node = rowbase + nl;
        H8 o;
        if (node < n) {
            float acc[8];
            if (h == 0) {
                H8 u;
                u.f4 = h4[(size_t)node * LPN + fg];  // self loop
#pragma unroll
                for (int q = 0; q < 4; ++q) {
                    float2 f = __half22float2(u.h2[q]);
                    acc[2 * q + 0] = f.x;
                    acc[2 * q + 1] = f.y;
                }
            } else {
#pragma unroll
                for (int q = 0; q < 8; ++q) acc[q] = 0.f;
            }
            int beg = row_ptr[node];
            int cn = rcnt[node];
            int j, end;
            if (HALVES == 2) {
                int midc = (cn + 1) >> 1;
                j   = beg + (h ? midc : 0);
                end = beg + (h ? cn : midc);
            } else {
                j = beg; end = beg + cn;
            }
            for (; j + 3 < end; j += 4) {
                int s0 = col[j], s1 = col[j + 1], s2 = col[j + 2], s3 = col[j + 3];
                H8 u0, u1, u2, u3;
                u0.f4 = h4[(size_t)s0 * LPN + fg];
                u1.f4 = h4[(size_t)s1 * LPN + fg];
                u2.f4 = h4[(size_t)s2 * LPN + fg];
                u3.f4 = h4[(size_t)s3 * LPN + fg];
#pragma unroll
                for (int q = 0; q < 4; ++q) {
                    float2 f0 = __half22float2(u0.h2[q]);
                    float2 f1 = __half22float2(u1.h2[q]);
                    float2 f2 = __half22float2(u2.h2[q]);
                    float2 f3 = __half22float2(u3.h2[q]);
                    acc[2 * q + 0] += (f0.x + f1.x) + (f2.x + f3.x);
                    acc[2 * q + 1] += (f0.y + f1.y) + (f2.y + f3.y);
                }
            }
            for (; j < end; ++j) {
                H8 u2;
                u2.f4 = h4[(size_t)col[j] * LPN + fg];
#pragma unroll
                for (int q = 0; q < 4; ++q) {
                    float2 f = __half22float2(u2.h2[q]);
                    acc[2 * q + 0] += f.x;
                    acc[2 * q + 1] += f.y;
                }
            }
            if (HALVES == 2) {
#pragma unroll
                for (int q = 0; q < 8; ++q) acc[q] += __shfl_xor(acc[q], 1);
            }
            float dsc = dinv[node];
#pragma unroll
            for (int q = 0; q < 4; ++q) {
                float v0 = fmaxf(fmaf(acc[2 * q + 0], dsc, bias[fg * 8 + 2 * q + 0]), 0.f);
                float v1 = fmaxf(fmaf(acc[2 * q + 1], dsc, bias[fg * 8 + 2 * q + 1]), 0.f);
                o.h2[q] = __floats2half2_rn(v0, v1);
            }
        } else {
            o.f4 = make_float4(0.f, 0.f, 0.f, 0.f);
        }
        if (h == 0) *(float4*)&zs[nl * LDH + fg * 8] = o.f4;
    }
    __syncthreads();

    // ---- MFMA: hs' = half((z @ W) * dinv[row]) (4 waves suffice) ----
    int lane = tid & 63;
    int wave = tid >> 6;
    if (wave >= 4) return;
    int m = lane & 15, quad = lane >> 4;
    int rg = wave >> 1;
    int th = wave & 1;

    floatx4 acc[TPW];
#pragma unroll
    for (int t = 0; t < TPW; ++t) acc[t] = (floatx4){0.f, 0.f, 0.f, 0.f};

    const half8* Wf = (const half8*)Wpk;
#pragma unroll
    for (int s = 0; s < S; ++s) {
        half8 a = *(const half8*)&zs[(rg * 16 + m) * LDH + s * 32 + quad * 8];
#pragma unroll
        for (int t = 0; t < TPW; ++t) {
            half8 b = Wf[(s * NT + th * TPW + t) * 64 + lane];
            acc[t] = __builtin_amdgcn_mfma_f32_16x16x32_f16(a, b, acc[t], 0, 0, 0);
        }
    }

    int rbase = rowbase + rg * 16 + quad * 4;
#pragma unroll
    for (int r = 0; r < 4; ++r) {
        int row = rbase + r;
        if (row < n) {
            float dsc = dinv[row];
#pragma unroll
            for (int t = 0; t < TPW; ++t)
                out[(size_t)row * OUT + (th * TPW + t) * 16 + m] = __float2half(acc[t][r] * dsc);
        }
    }
}

// ------- fused layer-3 aggregate + link head (F=32) ------------------------
// 8 lanes/node: sub = (fg<<1)|h; h-halves of the edge list combined via
// shfl_xor(1); dot reduced across fg via shfl_xor(2)+shfl_xor(4).
__global__ __launch_bounds__(256) void k_agg_final(const __half* __restrict__ hs,
                                                   const float* __restrict__ dinv,
                                                   const float* __restrict__ bias,
                                                   const int* __restrict__ row_ptr,
                                                   const int* __restrict__ rcnt,
                                                   const int* __restrict__ col,
                                                   const float* __restrict__ Wl,
                                                   const float* __restrict__ bl,
                                                   float* __restrict__ out, int n) {
    constexpr int LPN = 4;  // 32 feats / 8
    int t = blockIdx.x * 256 + threadIdx.x;
    int node = t >> 3;
    int sub = t & 7;
    int h = sub & 1;
    int fg = sub >> 1;
    if (node >= n) return;

    const float4* h4 = (const float4*)hs;
    float acc[8];
    if (h == 0) {
        H8 u;
        u.f4 = h4[(size_t)node * LPN + fg];
#pragma unroll
        for (int q = 0; q < 4; ++q) {
            float2 f = __half22float2(u.h2[q]);
            acc[2 * q + 0] = f.x;
            acc[2 * q + 1] = f.y;
        }
    } else {
#pragma unroll
        for (int q = 0; q < 8; ++q) acc[q] = 0.f;
    }
    int beg = row_ptr[node];
    int cn = rcnt[node];
    int midc = (cn + 1) >> 1;
    int j   = beg + (h ? midc : 0);
    int end = beg + (h ? cn : midc);
    for (; j + 3 < end; j += 4) {
        int s0 = col[j], s1 = col[j + 1], s2 = col[j + 2], s3 = col[j + 3];
        H8 u0, u1, u2, u3;
        u0.f4 = h4[(size_t)s0 * LPN + fg];
        u1.f4 = h4[(size_t)s1 * LPN + fg];
        u2.f4 = h4[(size_t)s2 * LPN + fg];
        u3.f4 = h4[(size_t)s3 * LPN + fg];
#pragma unroll
        for (int q = 0; q < 4; ++q) {
            float2 f0 = __half22float2(u0.h2[q]);
            float2 f1 = __half22float2(u1.h2[q]);
            float2 f2 = __half22float2(u2.h2[q]);
            float2 f3 = __half22float2(u3.h2[q]);
            acc[2 * q + 0] += (f0.x + f1.x) + (f2.x + f3.x);
            acc[2 * q + 1] += (f0.y + f1.y) + (f2.y + f3.y);
        }
    }
    for (; j < end; ++j) {
        H8 u;
        u.f4 = h4[(size_t)col[j] * LPN + fg];
#pragma unroll
        for (int q = 0; q < 4; ++q) {
            float2 f = __half22float2(u.h2[q]);
            acc[2 * q + 0] += f.x;
            acc[2 * q + 1] += f.y;
        }
    }
    // combine edge-halves (partner lane = tid^1, same node/fg)
#pragma unroll
    for (int q = 0; q < 8; ++q) acc[q] += __shfl_xor(acc[q], 1);

    float dsc = dinv[node];
    float partial = 0.f;
#pragma unroll
    for (int k = 0; k < 8; ++k) {
        float v = fmaxf(fmaf(acc[k], dsc, bias[fg * 8 + k]), 0.f);
        partial = fmaf(v, Wl[fg * 8 + k], partial);
    }
    // reduce across the 4 fg groups (each counted once per h-parity chain)
    partial += __shfl_xor(partial, 2);
    partial += __shfl_xor(partial, 4);
    if (sub == 0) out[node] = 1.f / (1.f + expf(-(partial + bl[0])));
}

extern "C" void kernel_launch(void* const* d_in, const int* in_sizes, int n_in,
                              void* d_out, int out_size, void* d_ws, size_t ws_size,
                              hipStream_t stream) {
    const float* x  = (const float*)d_in[0];
    const int*   ei = (const int*)d_in[1];
    const float* W1 = (const float*)d_in[2];
    const float* b1 = (const float*)d_in[3];
    const float* W2 = (const float*)d_in[4];
    const float* b2 = (const float*)d_in[5];
    const float* W3 = (const float*)d_in[6];
    const float* b3 = (const float*)d_in[7];
    const float* Wl = (const float*)d_in[8];
    const float* bl = (const float*)d_in[9];

    const int N = in_sizes[0] / 128;
    const int E = in_sizes[1] / 2;
    const int* src = ei;
    const int* dst = ei + E;
    const int B = (N + BNODES - 1) >> BSHIFT;  // <= 512 for N <= 131072

    char* ws = (char*)d_ws;
    size_t off = 0;
    auto take = [&](size_t bytes) -> char* {
        char* p = ws + off;
        off += (bytes + 255) & ~(size_t)255;
        return p;
    };
    int*          cursor  = (int*)take(MAXB * 4);
    unsigned int* edgebuf = (unsigned int*)take((size_t)B * CAP * 4);
    int*          row_ptr = (int*)take((size_t)N * 4);
    int*          rcnt    = (int*)take((size_t)N * 4);
    float*        dinv    = (float*)take((size_t)N * 4);
    int*          col     = (int*)take((size_t)B * CAP * 4);
    __half*       bufA    = (__half*)take((size_t)N * 128 * 2);
    __half*       bufB    = (__half*)take((size_t)N * 128 * 2);
    _Float16*     Wpk1    = (_Float16*)take(128 * 128 * 2);
    _Float16*     Wpk2    = (_Float16*)take(128 * 64 * 2);
    _Float16*     Wpk3    = (_Float16*)take(64 * 32 * 2);
    (void)ws_size;

    hipMemsetAsync(cursor, 0, MAXB * 4, stream);

    int gM = (N + 31) / 32;
    int nb = (E + 4095) / 4096;            // bucket-partition blocks
    int npack = (26624 + 255) / 256;       // weight-pack blocks (folded)

    // ---- CSR build (2 passes) + weight pack folded into k_bucket ----
    k_bucket<<<nb + npack, 256, 0, stream>>>(src, dst, E, cursor, edgebuf, B, nb,
                                             W1, W2, W3, Wpk1, Wpk2, Wpk3);
    k_build<<<B, 256, 0, stream>>>(edgebuf, cursor, row_ptr, rcnt, dinv, col, N);

    // ---- Layer 1 matmul: x (fp32) -> hs1 (bufA, F=128) ----
    k_matmul_mfma<128, 128><<<gM, 256, 0, stream>>>(x, Wpk1, dinv, bufA, N);

    // ---- agg1 (F=128, sentinel: unchanged) + mm2: bufA -> hs2 (bufB) ----
    k_agg_mm<128, 64, 256, 1><<<gM, 256, 0, stream>>>(bufA, dinv, b1, row_ptr, rcnt, col, Wpk2, bufB, N);

    // ---- agg2 (F=64, 2-lane edge-split) + mm3: bufB -> hs3 (bufA) ----
    k_agg_mm<64, 32, 512, 2><<<gM, 512, 0, stream>>>(bufB, dinv, b2, row_ptr, rcnt, col, Wpk3, bufA, N);

    // ---- agg3 (F=32, 8 lanes/node) + link head -> out ----
    k_agg_final<<<((size_t)N * 8 + 255) / 256, 256, 0, stream>>>(
        bufA, dinv, b3, row_ptr, rcnt, col, Wl, bl, (float*)d_out, N);
}

// Round 11
// 275.715 us; speedup vs baseline: 1.0217x; 1.0217x over previous
//
#include <hip/hip_runtime.h>
#include <hip/hip_fp16.h>
#include <math.h>

// ---------------------------------------------------------------------------
// GCN 3-layer: out = sigmoid( L3(relu(L2(relu(L1(x))))) @ Wl + bl )
// hs = half((x @ W) * dinv[row]);  z = relu(dinv[d]*(hs[d]+sum hs[s])+b)
// fp32 accumulate, fp16 storage.
// FINAL LEDGER (R1-R10) on the aggregation gathers (the dominant cost,
// running at the random-256B-line fabric rate ~2.9 TB/s L2-fill /
// ~6.8 TB/s delivered):
//   +waves        flat   (R1: occ 55->77%, dur unchanged)
//   +per-wave ILP worse  (R3: unroll-8, VGPR 32->52, 64->71.5us)
//   -compulsory bytes worse (R4: XCD feature-split, FETCH -10% dur +62%)
//   L2-bypass     worse  (R8: nt loads, 64.5->88.9us)
//   lane-split    worse  (R10: 2 lanes/node edge halves, +7us total)
// Harness re-poison fill = 40.5us fixed in the timed window (R6).
// CSR: 2-pass fixed-CAP bucket build (R9, -11.5us vs 4-pass; R2 proved
// direct global scatter costs ~170us in line-RMW).
// R11 = R9 verbatim (best verified, 274.75us). All components at their
// measured pattern-rate floors.
// ---------------------------------------------------------------------------

#define BSHIFT 8
#define BNODES (1 << BSHIFT)
#define SRCBITS 17
#define MAXB 512
#define CAP 8192

typedef _Float16 half8 __attribute__((ext_vector_type(8)));
typedef float floatx4 __attribute__((ext_vector_type(4)));

union H8 { float4 f4; __half2 h2[4]; };

// ---- k_bucket: blocks [0,nb) partition 4096 edges each into fixed-CAP
// bucket regions (one global atomic reservation per touched bucket);
// blocks [nb, nb+npack) pack W1/W2/W3 into fp16 MFMA B-fragment order. ----
__global__ __launch_bounds__(256) void k_bucket(const int* __restrict__ src,
                                                const int* __restrict__ dst, int E,
                                                int* __restrict__ cursor,
                                                unsigned int* __restrict__ edgebuf,
                                                int B, int nb,
                                                const float* __restrict__ W1,
                                                const float* __restrict__ W2,
                                                const float* __restrict__ W3,
                                                _Float16* __restrict__ P1,
                                                _Float16* __restrict__ P2,
                                                _Float16* __restrict__ P3) {
    int tid = threadIdx.x;
    if (blockIdx.x >= nb) {
        int e = (blockIdx.x - nb) * 256 + tid;
        const float* W; _Float16* P; int OUT, idx;
        if (e < 16384)      { W = W1; P = P1; OUT = 128; idx = e; }
        else if (e < 24576) { W = W2; P = P2; OUT = 64;  idx = e - 16384; }
        else if (e < 26624) { W = W3; P = P3; OUT = 32;  idx = e - 24576; }
        else return;
        int j = idx & 7;
        int lane = (idx >> 3) & 63;
        int rest = idx >> 9;
        int NT2 = OUT >> 4;
        int t = rest % NT2;
        int ss = rest / NT2;
        int k = ss * 32 + (lane >> 4) * 8 + j;
        int nn = t * 16 + (lane & 15);
        P[idx] = (_Float16)W[k * OUT + nn];
        return;
    }
    __shared__ int h[MAXB];
    __shared__ int pos_[MAXB];
    int base = blockIdx.x * 4096;
    int end = min(base + 4096, E);
    h[tid] = 0; h[tid + 256] = 0;
    __syncthreads();
    for (int i = base + tid; i < end; i += 256)
        atomicAdd(&h[dst[i] >> BSHIFT], 1);
    __syncthreads();
    if (tid < B) pos_[tid] = (h[tid] > 0) ? atomicAdd(&cursor[tid], h[tid]) : 0;
    int t2 = tid + 256;
    if (t2 < B) pos_[t2] = (h[t2] > 0) ? atomicAdd(&cursor[t2], h[t2]) : 0;
    __syncthreads();
    for (int i = base + tid; i < end; i += 256) {
        int d = dst[i];
        int b = d >> BSHIFT;
        unsigned int pk = ((unsigned int)(d & (BNODES - 1)) << SRCBITS) | (unsigned int)src[i];
        int pos = atomicAdd(&pos_[b], 1);
        if (pos < CAP) edgebuf[(size_t)b * CAP + pos] = pk;   // overflow guard
    }
}

// ---- k_build: per bucket, per-node counts + local scan -> strided CSR ----
__global__ __launch_bounds__(256) void k_build(const unsigned int* __restrict__ edgebuf,
                                               const int* __restrict__ cursor,
                                               int* __restrict__ row_ptr,
                                               int* __restrict__ rcnt,
                                               float* __restrict__ dinv,
                                               int* __restrict__ col, int n) {
    __shared__ int cnt[BNODES];
    __shared__ int s[BNODES];
    int b = blockIdx.x;
    int tid = threadIdx.x;
    int node0 = b << BSHIFT;
    int count = min(cursor[b], CAP);
    size_t ebase = (size_t)b * CAP;
    cnt[tid] = 0;
    __syncthreads();
    for (int i = tid; i < count; i += 256)
        atomicAdd(&cnt[edgebuf[ebase + i] >> SRCBITS], 1);
    __syncthreads();
    int c = cnt[tid];
    s[tid] = c;
    __syncthreads();
    for (int off = 1; off < 256; off <<= 1) {
        int t = (tid >= off) ? s[tid - off] : 0;
        __syncthreads();
        s[tid] += t;
        __syncthreads();
    }
    int p = b * CAP + s[tid] - c;     // absolute position in strided col[]
    int node = node0 + tid;
    if (node < n) {
        row_ptr[node] = p;
        rcnt[node] = c;
        dinv[node] = rsqrtf((float)(c + 1));
    }
    cnt[tid] = p;
    __syncthreads();
    for (int i = tid; i < count; i += 256) {
        unsigned int pk = edgebuf[ebase + i];
        int pos = atomicAdd(&cnt[pk >> SRCBITS], 1);
        col[pos] = (int)(pk & ((1u << SRCBITS) - 1));
    }
}

// ---------------- MFMA matmul (layer 1): hs = half((x@W)*dinv[row]) -------
template <int IN, int OUT>
__global__ __launch_bounds__(256) void k_matmul_mfma(const float* __restrict__ x,
                                                     const _Float16* __restrict__ Wpk,
                                                     const float* __restrict__ dinv,
                                                     __half* __restrict__ out, int n) {
    constexpr int S = IN / 32;
    constexpr int NT = OUT / 16;
    constexpr int TPW = NT / 2;
    constexpr int LDH = IN + 8;
    __shared__ _Float16 xs[32 * LDH];

    int tid = threadIdx.x;
    int rowbase = blockIdx.x * 32;

    constexpr int TOT = 32 * IN / 8;
    const float4* x4 = (const float4*)x;
    for (int i = tid; i < TOT; i += 256) {
        int r = i / (IN / 8), kg = i % (IN / 8);
        int row = rowbase + r;
        float4 a = make_float4(0.f, 0.f, 0.f, 0.f), b = a;
        if (row < n) {
            a = x4[(size_t)row * (IN / 4) + kg * 2 + 0];
            b = x4[(size_t)row * (IN / 4) + kg * 2 + 1];
        }
        _Float16* p = &xs[r * LDH + kg * 8];
        p[0] = (_Float16)a.x; p[1] = (_Float16)a.y;
        p[2] = (_Float16)a.z; p[3] = (_Float16)a.w;
        p[4] = (_Float16)b.x; p[5] = (_Float16)b.y;
        p[6] = (_Float16)b.z; p[7] = (_Float16)b.w;
    }
    __syncthreads();

    int lane = tid & 63;
    int wave = tid >> 6;
    int m = lane & 15, quad = lane >> 4;
    int rg = wave >> 1;
    int th = wave & 1;

    floatx4 acc[TPW];
#pragma unroll
    for (int t = 0; t < TPW; ++t) acc[t] = (floatx4){0.f, 0.f, 0.f, 0.f};

    const half8* Wf = (const half8*)Wpk;
#pragma unroll
    for (int s = 0; s < S; ++s) {
        half8 a = *(const half8*)&xs[(rg * 16 + m) * LDH + s * 32 + quad * 8];
#pragma unroll
        for (int t = 0; t < TPW; ++t) {
            half8 b = Wf[(s * NT + th * TPW + t) * 64 + lane];
            acc[t] = __builtin_amdgcn_mfma_f32_16x16x32_f16(a, b, acc[t], 0, 0, 0);
        }
    }

    int rbase = rowbase + rg * 16 + quad * 4;
#pragma unroll
    for (int r = 0; r < 4; ++r) {
        int row = rbase + r;
        if (row < n) {
            float dsc = dinv[row];
#pragma unroll
            for (int t = 0; t < TPW; ++t)
                out[(size_t)row * OUT + (th * TPW + t) * 16 + m] = __float2half(acc[t][r] * dsc);
        }
    }
}

// ------- fused: z = relu(dinv*(agg hs)+b) in LDS, then hs' = (z@W)*dinv ----
// 32 dst rows/block; unroll-4 gather (R3: unroll-8 regressed; R8: nt loads
// regressed; R10: lane-split regressed). Extent via row_ptr + rcnt.
template <int F, int OUT>
__global__ __launch_bounds__(256) void k_agg_mm(const __half* __restrict__ hs,
                                                const float* __restrict__ dinv,
                                                const float* __restrict__ bias,
                                                const int* __restrict__ row_ptr,
                                                const int* __restrict__ rcnt,
                                                const int* __restrict__ col,
                                                const _Float16* __restrict__ Wpk,
                                                __half* __restrict__ out, int n) {
    constexpr int S = F / 32;
    constexpr int NT = OUT / 16;
    constexpr int TPW = NT / 2;
    constexpr int LDH = F + 8;
    constexpr int LPN = F / 8;
    __shared__ _Float16 zs[32 * LDH];

    int tid = threadIdx.x;
    int rowbase = blockIdx.x * 32;
    const float4* h4 = (const float4*)hs;

    // ---- aggregate 32 dst rows into LDS (fp32 acc, fp16 store) ----
    for (int task = tid; task < 32 * LPN; task += 256) {
        int nl = task / LPN;
        int fg = task % LPN;
        int node = rowbase + nl;
        H8 o;
        if (node < n) {
            float acc[8];
            H8 u;
            u.f4 = h4[(size_t)node * LPN + fg];  // self loop
#pragma unroll
            for (int q = 0; q < 4; ++q) {
                float2 f = __half22float2(u.h2[q]);
                acc[2 * q + 0] = f.x;
                acc[2 * q + 1] = f.y;
            }
            int beg = row_ptr[node];
            int end = beg + rcnt[node];
            int j = beg;
            for (; j + 3 < end; j += 4) {
                int s0 = col[j], s1 = col[j + 1], s2 = col[j + 2], s3 = col[j + 3];
                H8 u0, u1, u2, u3;
                u0.f4 = h4[(size_t)s0 * LPN + fg];
                u1.f4 = h4[(size_t)s1 * LPN + fg];
                u2.f4 = h4[(size_t)s2 * LPN + fg];
                u3.f4 = h4[(size_t)s3 * LPN + fg];
#pragma unroll
                for (int q = 0; q < 4; ++q) {
                    float2 f0 = __half22float2(u0.h2[q]);
                    float2 f1 = __half22float2(u1.h2[q]);
                    float2 f2 = __half22float2(u2.h2[q]);
                    float2 f3 = __half22float2(u3.h2[q]);
                    acc[2 * q + 0] += (f0.x + f1.x) + (f2.x + f3.x);
                    acc[2 * q + 1] += (f0.y + f1.y) + (f2.y + f3.y);
                }
            }
            for (; j < end; ++j) {
                H8 u2;
                u2.f4 = h4[(size_t)col[j] * LPN + fg];
#pragma unroll
                for (int q = 0; q < 4; ++q) {
                    float2 f = __half22float2(u2.h2[q]);
                    acc[2 * q + 0] += f.x;
                    acc[2 * q + 1] += f.y;
                }
            }
            float dsc = dinv[node];
#pragma unroll
            for (int q = 0; q < 4; ++q) {
                float v0 = fmaxf(fmaf(acc[2 * q + 0], dsc, bias[fg * 8 + 2 * q + 0]), 0.f);
                float v1 = fmaxf(fmaf(acc[2 * q + 1], dsc, bias[fg * 8 + 2 * q + 1]), 0.f);
                o.h2[q] = __floats2half2_rn(v0, v1);
            }
        } else {
            o.f4 = make_float4(0.f, 0.f, 0.f, 0.f);
        }
        *(float4*)&zs[nl * LDH + fg * 8] = o.f4;
    }
    __syncthreads();

    // ---- MFMA: hs' = half((z @ W) * dinv[row]) ----
    int lane = tid & 63;
    int wave = tid >> 6;
    int m = lane & 15, quad = lane >> 4;
    int rg = wave >> 1;
    int th = wave & 1;

    floatx4 acc[TPW];
#pragma unroll
    for (int t = 0; t < TPW; ++t) acc[t] = (floatx4){0.f, 0.f, 0.f, 0.f};

    const half8* Wf = (const half8*)Wpk;
#pragma unroll
    for (int s = 0; s < S; ++s) {
        half8 a = *(const half8*)&zs[(rg * 16 + m) * LDH + s * 32 + quad * 8];
#pragma unroll
        for (int t = 0; t < TPW; ++t) {
            half8 b = Wf[(s * NT + th * TPW + t) * 64 + lane];
            acc[t] = __builtin_amdgcn_mfma_f32_16x16x32_f16(a, b, acc[t], 0, 0, 0);
        }
    }

    int rbase = rowbase + rg * 16 + quad * 4;
#pragma unroll
    for (int r = 0; r < 4; ++r) {
        int row = rbase + r;
        if (row < n) {
            float dsc = dinv[row];
#pragma unroll
            for (int t = 0; t < TPW; ++t)
                out[(size_t)row * OUT + (th * TPW + t) * 16 + m] = __float2half(acc[t][r] * dsc);
        }
    }
}

// ------- fused layer-3 aggregate + link head (F=32) ------------------------
__global__ __launch_bounds__(256) void k_agg_final(const __half* __restrict__ hs,
                                                   const float* __restrict__ dinv,
                                                   const float* __restrict__ bias,
                                                   const int* __restrict__ row_ptr,
                                                   const int* __restrict__ rcnt,
                                                   const int* __restrict__ col,
                                                   const float* __restrict__ Wl,
                                                   const float* __restrict__ bl,
                                                   float* __restrict__ out, int n) {
    constexpr int LPN = 4;  // 32 feats / 8
    int t = blockIdx.x * 256 + threadIdx.x;
    int node = t / LPN;
    int fg = t % LPN;
    if (node >= n) return;

    const float4* h4 = (const float4*)hs;
    float acc[8];
    {
        H8 u;
        u.f4 = h4[(size_t)node * LPN + fg];
#pragma unroll
        for (int q = 0; q < 4; ++q) {
            float2 f = __half22float2(u.h2[q]);
            acc[2 * q + 0] = f.x;
            acc[2 * q + 1] = f.y;
        }
    }
    int beg = row_ptr[node];
    int end = beg + rcnt[node];
    int j = beg;
    for (; j + 3 < end; j += 4) {
        int s0 = col[j], s1 = col[j + 1], s2 = col[j + 2], s3 = col[j + 3];
        H8 u0, u1, u2, u3;
        u0.f4 = h4[(size_t)s0 * LPN + fg];
        u1.f4 = h4[(size_t)s1 * LPN + fg];
        u2.f4 = h4[(size_t)s2 * LPN + fg];
        u3.f4 = h4[(size_t)s3 * LPN + fg];
#pragma unroll
        for (int q = 0; q < 4; ++q) {
            float2 f0 = __half22float2(u0.h2[q]);
            float2 f1 = __half22float2(u1.h2[q]);
            float2 f2 = __half22float2(u2.h2[q]);
            float2 f3 = __half22float2(u3.h2[q]);
            acc[2 * q + 0] += (f0.x + f1.x) + (f2.x + f3.x);
            acc[2 * q + 1] += (f0.y + f1.y) + (f2.y + f3.y);
        }
    }
    for (; j < end; ++j) {
        H8 u;
        u.f4 = h4[(size_t)col[j] * LPN + fg];
#pragma unroll
        for (int q = 0; q < 4; ++q) {
            float2 f = __half22float2(u.h2[q]);
            acc[2 * q + 0] += f.x;
            acc[2 * q + 1] += f.y;
        }
    }
    float dsc = dinv[node];
    float partial = 0.f;
#pragma unroll
    for (int k = 0; k < 8; ++k) {
        float v = fmaxf(fmaf(acc[k], dsc, bias[fg * 8 + k]), 0.f);
        partial = fmaf(v, Wl[fg * 8 + k], partial);
    }
    partial += __shfl_xor(partial, 1);
    partial += __shfl_xor(partial, 2);
    if (fg == 0) out[node] = 1.f / (1.f + expf(-(partial + bl[0])));
}

extern "C" void kernel_launch(void* const* d_in, const int* in_sizes, int n_in,
                              void* d_out, int out_size, void* d_ws, size_t ws_size,
                              hipStream_t stream) {
    const float* x  = (const float*)d_in[0];
    const int*   ei = (const int*)d_in[1];
    const float* W1 = (const float*)d_in[2];
    const float* b1 = (const float*)d_in[3];
    const float* W2 = (const float*)d_in[4];
    const float* b2 = (const float*)d_in[5];
    const float* W3 = (const float*)d_in[6];
    const float* b3 = (const float*)d_in[7];
    const float* Wl = (const float*)d_in[8];
    const float* bl = (const float*)d_in[9];

    const int N = in_sizes[0] / 128;
    const int E = in_sizes[1] / 2;
    const int* src = ei;
    const int* dst = ei + E;
    const int B = (N + BNODES - 1) >> BSHIFT;  // <= 512 for N <= 131072

    char* ws = (char*)d_ws;
    size_t off = 0;
    auto take = [&](size_t bytes) -> char* {
        char* p = ws + off;
        off += (bytes + 255) & ~(size_t)255;
        return p;
    };
    int*          cursor  = (int*)take(MAXB * 4);
    unsigned int* edgebuf = (unsigned int*)take((size_t)B * CAP * 4);
    int*          row_ptr = (int*)take((size_t)N * 4);
    int*          rcnt    = (int*)take((size_t)N * 4);
    float*        dinv    = (float*)take((size_t)N * 4);
    int*          col     = (int*)take((size_t)B * CAP * 4);
    __half*       bufA    = (__half*)take((size_t)N * 128 * 2);
    __half*       bufB    = (__half*)take((size_t)N * 128 * 2);
    _Float16*     Wpk1    = (_Float16*)take(128 * 128 * 2);
    _Float16*     Wpk2    = (_Float16*)take(128 * 64 * 2);
    _Float16*     Wpk3    = (_Float16*)take(64 * 32 * 2);
    (void)ws_size;

    hipMemsetAsync(cursor, 0, MAXB * 4, stream);

    int gM = (N + 31) / 32;
    int nb = (E + 4095) / 4096;            // bucket-partition blocks
    int npack = (26624 + 255) / 256;       // weight-pack blocks (folded)

    // ---- CSR build (2 passes) + weight pack folded into k_bucket ----
    k_bucket<<<nb + npack, 256, 0, stream>>>(src, dst, E, cursor, edgebuf, B, nb,
                                             W1, W2, W3, Wpk1, Wpk2, Wpk3);
    k_build<<<B, 256, 0, stream>>>(edgebuf, cursor, row_ptr, rcnt, dinv, col, N);

    // ---- Layer 1 matmul: x (fp32) -> hs1 (bufA, F=128) ----
    k_matmul_mfma<128, 128><<<gM, 256, 0, stream>>>(x, Wpk1, dinv, bufA, N);

    // ---- agg1 (F=128) + mm2 (128->64): bufA -> hs2 (bufB) ----
    k_agg_mm<128, 64><<<gM, 256, 0, stream>>>(bufA, dinv, b1, row_ptr, rcnt, col, Wpk2, bufB, N);

    // ---- agg2 (F=64) + mm3 (64->32): bufB -> hs3 (bufA) ----
    k_agg_mm<64, 32><<<gM, 256, 0, stream>>>(bufB, dinv, b2, row_ptr, rcnt, col, Wpk3, bufA, N);

    // ---- agg3 (F=32) + link head -> out ----
    k_agg_final<<<((size_t)N * 4 + 255) / 256, 256, 0, stream>>>(
        bufA, dinv, b3, row_ptr, rcnt, col, Wl, bl, (float*)d_out, N);
}